// Round 1
// baseline (6183.141 us; speedup 1.0000x reference)
//
#include <hip/hip_runtime.h>
#include <math.h>

#define NN 50000
#define NE 800000
#define DIM 128
#define NH 8
#define HD 16

// ---- float <-> order-preserving unsigned (for atomicMax on floats) ----
__device__ __forceinline__ unsigned enc_f32(float f) {
    unsigned u = __float_as_uint(f);
    return (u & 0x80000000u) ? ~u : (u | 0x80000000u);
}
__device__ __forceinline__ float dec_f32(unsigned u) {
    return (u & 0x80000000u) ? __uint_as_float(u & 0x7fffffffu)
                             : __uint_as_float(~u);
}

// ---- K1: fused QKV projection (x @ W.T + b) + workspace init ----
__global__ __launch_bounds__(256) void qkv_init_kernel(
    const float* __restrict__ x,
    const float* __restrict__ Wq, const float* __restrict__ bq,
    const float* __restrict__ Wk, const float* __restrict__ bk,
    const float* __restrict__ Wv, const float* __restrict__ bv,
    float* __restrict__ q, float* __restrict__ k, float* __restrict__ v,
    unsigned* __restrict__ m, float* __restrict__ s, float* __restrict__ agg)
{
    __shared__ float xs[32 * DIM];
    const int node0 = blockIdx.x * 32;
    const int tid = threadIdx.x;
    const int nvalid = min(32, NN - node0);

    // load x tile (32 rows x 128 cols) as float4, zero-pad invalid rows
    for (int i = tid; i < 32 * 32; i += 256) {
        int r = i >> 5;
        float4 val = make_float4(0.f, 0.f, 0.f, 0.f);
        if (r < nvalid)
            val = ((const float4*)(x + (size_t)(node0 + r) * DIM))[i & 31];
        ((float4*)xs)[i] = val;
    }
    // init m (encoded -inf == 0) and s
    {
        int n = node0 + (tid >> 3);
        if (n < NN) {
            m[n * NH + (tid & 7)] = 0u;
            s[n * NH + (tid & 7)] = 0.f;
        }
    }
    // init agg
    for (int i = tid; i < 32 * DIM; i += 256) {
        int r = i >> 7;
        if (node0 + r < NN)
            agg[(size_t)(node0 + r) * DIM + (i & 127)] = 0.f;
    }
    __syncthreads();

    const int j = tid & 127;      // output column
    const int half = tid >> 7;    // rows half*16 .. half*16+15

    const float* Ws[3] = {Wq, Wk, Wv};
    const float* bs[3] = {bq, bk, bv};
    float* outs[3] = {q, k, v};

    for (int w = 0; w < 3; ++w) {
        float acc[16];
#pragma unroll
        for (int i = 0; i < 16; ++i) acc[i] = 0.f;
        const float* Wrow = Ws[w] + (size_t)j * DIM;
#pragma unroll 4
        for (int d = 0; d < DIM; d += 4) {
            float4 w4 = *(const float4*)(Wrow + d);
#pragma unroll
            for (int i = 0; i < 16; ++i) {
                const float* xr = xs + (half * 16 + i) * DIM + d;
                acc[i] += w4.x * xr[0] + w4.y * xr[1] + w4.z * xr[2] + w4.w * xr[3];
            }
        }
        float bias = bs[w][j];
#pragma unroll
        for (int i = 0; i < 16; ++i) {
            int n = node0 + half * 16 + i;
            if (n < NN) outs[w][(size_t)n * DIM + j] = acc[i] + bias;
        }
    }
}

// ---- K2: edge scores + segment max (atomicMax on encoded float) ----
__global__ __launch_bounds__(256) void score_kernel(
    const int* __restrict__ tgt, const int* __restrict__ src,
    const float* __restrict__ q, const float* __restrict__ k,
    float* __restrict__ scores, unsigned* __restrict__ m)
{
    int t = blockIdx.x * 256 + threadIdx.x;
    if (t >= NE * NH) return;
    int e = t >> 3, h = t & 7;
    int ts = tgt[e], ss = src[e];
    const float4* qp = (const float4*)(q + (size_t)ss * DIM + h * HD);
    const float4* kp = (const float4*)(k + (size_t)ts * DIM + h * HD);
    float d = 0.f;
#pragma unroll
    for (int i = 0; i < 4; ++i) {
        float4 a = qp[i], b = kp[i];
        d += a.x * b.x + a.y * b.y + a.z * b.z + a.w * b.w;
    }
    float sc = d * 0.25f;   // 1/sqrt(16)
    scores[t] = sc;
    atomicMax(m + (size_t)ts * NH + h, enc_f32(sc));
}

// ---- K3: p = exp(score - m[tgt]); segment sum ----
__global__ __launch_bounds__(256) void expsum_kernel(
    const int* __restrict__ tgt,
    float* __restrict__ scores,          // in: score, out: p
    const unsigned* __restrict__ m, float* __restrict__ s)
{
    int t = blockIdx.x * 256 + threadIdx.x;
    if (t >= NE * NH) return;
    int e = t >> 3, h = t & 7;
    int ts = tgt[e];
    float mm = dec_f32(m[(size_t)ts * NH + h]);
    float p = __expf(scores[t] - mm);
    scores[t] = p;
    atomicAdd(s + (size_t)ts * NH + h, p);
}

// ---- K4: agg[tgt] += v[src] * (p / s[tgt]) ----
__global__ __launch_bounds__(256) void scatter_kernel(
    const int* __restrict__ tgt, const int* __restrict__ src,
    const float* __restrict__ scores,    // p
    const float* __restrict__ s,
    const float* __restrict__ v, float* __restrict__ agg)
{
    int t = blockIdx.x * 256 + threadIdx.x;
    if (t >= NE * NH) return;
    int e = t >> 3, h = t & 7;
    int ts = tgt[e], ss = src[e];
    float w = scores[t] / s[(size_t)ts * NH + h];
    const float4* vp = (const float4*)(v + (size_t)ss * DIM + h * HD);
    float* ap = agg + (size_t)ts * DIM + h * HD;
#pragma unroll
    for (int i = 0; i < 4; ++i) {
        float4 vv = vp[i];
        atomicAdd(ap + 4 * i + 0, vv.x * w);
        atomicAdd(ap + 4 * i + 1, vv.y * w);
        atomicAdd(ap + 4 * i + 2, vv.z * w);
        atomicAdd(ap + 4 * i + 3, vv.w * w);
    }
}

// ---- K5: out = agg @ Wo.T + bo ----
__global__ __launch_bounds__(256) void outproj_kernel(
    const float* __restrict__ agg, const float* __restrict__ Wo,
    const float* __restrict__ bo, float* __restrict__ out)
{
    __shared__ float xs[32 * DIM];
    const int node0 = blockIdx.x * 32;
    const int tid = threadIdx.x;
    const int nvalid = min(32, NN - node0);

    for (int i = tid; i < 32 * 32; i += 256) {
        int r = i >> 5;
        float4 val = make_float4(0.f, 0.f, 0.f, 0.f);
        if (r < nvalid)
            val = ((const float4*)(agg + (size_t)(node0 + r) * DIM))[i & 31];
        ((float4*)xs)[i] = val;
    }
    __syncthreads();

    const int j = tid & 127;
    const int half = tid >> 7;

    float acc[16];
#pragma unroll
    for (int i = 0; i < 16; ++i) acc[i] = 0.f;
    const float* Wrow = Wo + (size_t)j * DIM;
#pragma unroll 4
    for (int d = 0; d < DIM; d += 4) {
        float4 w4 = *(const float4*)(Wrow + d);
#pragma unroll
        for (int i = 0; i < 16; ++i) {
            const float* xr = xs + (half * 16 + i) * DIM + d;
            acc[i] += w4.x * xr[0] + w4.y * xr[1] + w4.z * xr[2] + w4.w * xr[3];
        }
    }
    float bias = bo[j];
#pragma unroll
    for (int i = 0; i < 16; ++i) {
        int n = node0 + half * 16 + i;
        if (n < NN) out[(size_t)n * DIM + j] = acc[i] + bias;
    }
}

extern "C" void kernel_launch(void* const* d_in, const int* in_sizes, int n_in,
                              void* d_out, int out_size, void* d_ws, size_t ws_size,
                              hipStream_t stream) {
    const float* x  = (const float*)d_in[0];
    const int*   ei = (const int*)d_in[1];      // [2, NE]: row0 = tgt, row1 = src
    const float* Wq = (const float*)d_in[2];
    const float* bq = (const float*)d_in[3];
    const float* Wk = (const float*)d_in[4];
    const float* bk = (const float*)d_in[5];
    const float* Wv = (const float*)d_in[6];
    const float* bv = (const float*)d_in[7];
    const float* Wo = (const float*)d_in[8];
    const float* bo = (const float*)d_in[9];

    const int* tgt = ei;
    const int* src = ei + NE;

    char* ws = (char*)d_ws;
    const size_t SZ_NODE = (size_t)NN * DIM * sizeof(float);   // 25.6 MB
    const size_t SZ_EDGE = (size_t)NE * NH * sizeof(float);    // 25.6 MB
    const size_t SZ_NH   = (size_t)NN * NH * sizeof(float);    // 1.6 MB

    float*    q      = (float*)(ws);
    float*    k      = (float*)(ws + SZ_NODE);
    float*    v      = (float*)(ws + 2 * SZ_NODE);
    float*    scores = (float*)(ws + 3 * SZ_NODE);
    float*    agg    = (float*)(ws + 3 * SZ_NODE + SZ_EDGE);
    unsigned* m      = (unsigned*)(ws + 4 * SZ_NODE + SZ_EDGE);
    float*    s      = (float*)(ws + 4 * SZ_NODE + SZ_EDGE + SZ_NH);

    const int node_blocks = (NN + 31) / 32;        // 1563
    const int edge_blocks = (NE * NH + 255) / 256; // 25000

    qkv_init_kernel<<<node_blocks, 256, 0, stream>>>(
        x, Wq, bq, Wk, bk, Wv, bv, q, k, v, m, s, agg);
    score_kernel<<<edge_blocks, 256, 0, stream>>>(tgt, src, q, k, scores, m);
    expsum_kernel<<<edge_blocks, 256, 0, stream>>>(tgt, scores, m, s);
    scatter_kernel<<<edge_blocks, 256, 0, stream>>>(tgt, src, scores, s, v, agg);
    outproj_kernel<<<node_blocks, 256, 0, stream>>>(agg, Wo, bo, (float*)d_out);
}

// Round 2
// 543.658 us; speedup vs baseline: 11.3732x; 11.3732x over previous
//
#include <hip/hip_runtime.h>
#include <math.h>

#define NN 50000
#define NE 800000
#define DIM 128
#define NH 8
#define HD 16

// ---- K1: fused QKV projection (x @ W.T + b) + zero edge counters ----
__global__ __launch_bounds__(256) void qkv_init_kernel(
    const float* __restrict__ x,
    const float* __restrict__ Wq, const float* __restrict__ bq,
    const float* __restrict__ Wk, const float* __restrict__ bk,
    const float* __restrict__ Wv, const float* __restrict__ bv,
    float* __restrict__ q, float* __restrict__ k, float* __restrict__ v,
    int* __restrict__ cnt)
{
    __shared__ float xs[32 * DIM];
    const int node0 = blockIdx.x * 32;
    const int tid = threadIdx.x;
    const int nvalid = min(32, NN - node0);

    // load x tile (32 rows x 128 cols) as float4, zero-pad invalid rows
    for (int i = tid; i < 32 * 32; i += 256) {
        int r = i >> 5;
        float4 val = make_float4(0.f, 0.f, 0.f, 0.f);
        if (r < nvalid)
            val = ((const float4*)(x + (size_t)(node0 + r) * DIM))[i & 31];
        ((float4*)xs)[i] = val;
    }
    if (tid < 32 && node0 + tid < NN) cnt[node0 + tid] = 0;
    __syncthreads();

    const int j = tid & 127;      // output column
    const int half = tid >> 7;    // rows half*16 .. half*16+15

    const float* Ws[3] = {Wq, Wk, Wv};
    const float* bs[3] = {bq, bk, bv};
    float* outs[3] = {q, k, v};

    for (int w = 0; w < 3; ++w) {
        float acc[16];
#pragma unroll
        for (int i = 0; i < 16; ++i) acc[i] = 0.f;
        const float* Wrow = Ws[w] + (size_t)j * DIM;
#pragma unroll 4
        for (int d = 0; d < DIM; d += 4) {
            float4 w4 = *(const float4*)(Wrow + d);
#pragma unroll
            for (int i = 0; i < 16; ++i) {
                const float* xr = xs + (half * 16 + i) * DIM + d;
                acc[i] += w4.x * xr[0] + w4.y * xr[1] + w4.z * xr[2] + w4.w * xr[3];
            }
        }
        float bias = bs[w][j];
#pragma unroll
        for (int i = 0; i < 16; ++i) {
            int n = node0 + half * 16 + i;
            if (n < NN) outs[w][(size_t)n * DIM + j] = acc[i] + bias;
        }
    }
}

// ---- K2: histogram of edges per target node ----
__global__ __launch_bounds__(256) void hist_kernel(
    const int* __restrict__ tgt, int* __restrict__ cnt)
{
    int e = blockIdx.x * 256 + threadIdx.x;
    if (e < NE) atomicAdd(cnt + tgt[e], 1);
}

// ---- K3: single-block exclusive scan (shfl-based) -> off, cursor ----
__global__ __launch_bounds__(1024) void scan_kernel(
    const int* __restrict__ cnt, int* __restrict__ off, int* __restrict__ cursor)
{
    __shared__ int wsum[16];
    __shared__ int carry_s;
    const int tid = threadIdx.x;
    const int lane = tid & 63;
    const int wid = tid >> 6;
    if (tid == 0) carry_s = 0;
    __syncthreads();
    for (int base = 0; base < NN; base += 1024) {
        int i = base + tid;
        int orig = (i < NN) ? cnt[i] : 0;
        int v = orig;
        // per-wave inclusive scan
#pragma unroll
        for (int d = 1; d < 64; d <<= 1) {
            int t = __shfl_up(v, d);
            if (lane >= d) v += t;
        }
        if (lane == 63) wsum[wid] = v;
        __syncthreads();
        if (wid == 0) {
            int wv = (lane < 16) ? wsum[lane] : 0;
#pragma unroll
            for (int d = 1; d < 16; d <<= 1) {
                int t = __shfl_up(wv, d);
                if (lane >= d) wv += t;
            }
            if (lane < 16) wsum[lane] = wv;   // inclusive wave totals
        }
        __syncthreads();
        int wave_excl = (wid == 0) ? 0 : wsum[wid - 1];
        int carry = carry_s;
        int excl = carry + wave_excl + (v - orig);
        if (i < NN) { off[i] = excl; cursor[i] = excl; }
        __syncthreads();
        if (tid == 1023) carry_s = carry + wsum[15];
    }
    __syncthreads();
    if (tid == 0) off[NN] = carry_s;
}

// ---- K4: fill CSR: edge_src[pos] = src[e], bucketed by tgt ----
__global__ __launch_bounds__(256) void fill_kernel(
    const int* __restrict__ tgt, const int* __restrict__ src,
    int* __restrict__ cursor, int* __restrict__ edge_src)
{
    int e = blockIdx.x * 256 + threadIdx.x;
    if (e >= NE) return;
    int t = tgt[e];
    int pos = atomicAdd(cursor + t, 1);
    edge_src[pos] = src[e];
}

// ---- K5: pull-mode fused attention: one wave per target node ----
// lane = h*8 + j : 8 lanes per head, online softmax over incoming edges
__global__ __launch_bounds__(256) void attn_pull_kernel(
    const int* __restrict__ off, const int* __restrict__ edge_src,
    const float* __restrict__ q, const float* __restrict__ k,
    const float* __restrict__ v, float* __restrict__ agg)
{
    const int node = (blockIdx.x * 256 + threadIdx.x) >> 6;  // one wave per node
    const int lane = threadIdx.x & 63;
    const int h = lane >> 3;
    const int j = lane & 7;

    const int base = off[node];
    const int deg = off[node + 1] - base;
    float* aggp = agg + (size_t)node * DIM + h * HD;

    if (deg == 0) {
        if (j == 0) {
            float4 z = make_float4(0.f, 0.f, 0.f, 0.f);
#pragma unroll
            for (int i = 0; i < 4; ++i) ((float4*)aggp)[i] = z;
        }
        return;
    }

    // k[node] fragment for this head, register-resident
    float kf[16];
    {
        const float4* kp = (const float4*)(k + (size_t)node * DIM + h * HD);
#pragma unroll
        for (int i = 0; i < 4; ++i) {
            float4 kk = kp[i];
            kf[4*i+0] = kk.x; kf[4*i+1] = kk.y; kf[4*i+2] = kk.z; kf[4*i+3] = kk.w;
        }
    }

    float m = -1e30f, s = 0.f;
    float acc[16];
#pragma unroll
    for (int i = 0; i < 16; ++i) acc[i] = 0.f;

    for (int i = j; i < deg; i += 8) {
        int ss = edge_src[base + i];
        const float4* qp = (const float4*)(q + (size_t)ss * DIM + h * HD);
        float sc = 0.f;
#pragma unroll
        for (int u = 0; u < 4; ++u) {
            float4 qq = qp[u];
            sc += qq.x * kf[4*u+0] + qq.y * kf[4*u+1]
                + qq.z * kf[4*u+2] + qq.w * kf[4*u+3];
        }
        sc *= 0.25f;   // 1/sqrt(HD)
        float nm = fmaxf(m, sc);
        float corr = __expf(m - nm);
        float p = __expf(sc - nm);
        s = s * corr + p;
        const float4* vp = (const float4*)(v + (size_t)ss * DIM + h * HD);
#pragma unroll
        for (int u = 0; u < 4; ++u) {
            float4 vv = vp[u];
            acc[4*u+0] = acc[4*u+0] * corr + p * vv.x;
            acc[4*u+1] = acc[4*u+1] * corr + p * vv.y;
            acc[4*u+2] = acc[4*u+2] * corr + p * vv.z;
            acc[4*u+3] = acc[4*u+3] * corr + p * vv.w;
        }
        m = nm;
    }

    // merge online-softmax states across the 8 lanes of this head group
#pragma unroll
    for (int d = 1; d < 8; d <<= 1) {
        float om = __shfl_xor(m, d);
        float os = __shfl_xor(s, d);
        float nm = fmaxf(m, om);
        float c1 = __expf(m - nm);
        float c2 = __expf(om - nm);
        s = s * c1 + os * c2;
#pragma unroll
        for (int x = 0; x < 16; ++x) {
            float oa = __shfl_xor(acc[x], d);
            acc[x] = acc[x] * c1 + oa * c2;
        }
        m = nm;
    }

    if (j == 0) {
        float inv = 1.f / s;
#pragma unroll
        for (int i = 0; i < 4; ++i) {
            float4 o;
            o.x = acc[4*i+0] * inv; o.y = acc[4*i+1] * inv;
            o.z = acc[4*i+2] * inv; o.w = acc[4*i+3] * inv;
            ((float4*)aggp)[i] = o;
        }
    }
}

// ---- K6: out = agg @ Wo.T + bo ----
__global__ __launch_bounds__(256) void outproj_kernel(
    const float* __restrict__ agg, const float* __restrict__ Wo,
    const float* __restrict__ bo, float* __restrict__ out)
{
    __shared__ float xs[32 * DIM];
    const int node0 = blockIdx.x * 32;
    const int tid = threadIdx.x;
    const int nvalid = min(32, NN - node0);

    for (int i = tid; i < 32 * 32; i += 256) {
        int r = i >> 5;
        float4 val = make_float4(0.f, 0.f, 0.f, 0.f);
        if (r < nvalid)
            val = ((const float4*)(agg + (size_t)(node0 + r) * DIM))[i & 31];
        ((float4*)xs)[i] = val;
    }
    __syncthreads();

    const int j = tid & 127;
    const int half = tid >> 7;

    float acc[16];
#pragma unroll
    for (int i = 0; i < 16; ++i) acc[i] = 0.f;
    const float* Wrow = Wo + (size_t)j * DIM;
#pragma unroll 4
    for (int d = 0; d < DIM; d += 4) {
        float4 w4 = *(const float4*)(Wrow + d);
#pragma unroll
        for (int i = 0; i < 16; ++i) {
            const float* xr = xs + (half * 16 + i) * DIM + d;
            acc[i] += w4.x * xr[0] + w4.y * xr[1] + w4.z * xr[2] + w4.w * xr[3];
        }
    }
    float bias = bo[j];
#pragma unroll
    for (int i = 0; i < 16; ++i) {
        int n = node0 + half * 16 + i;
        if (n < NN) out[(size_t)n * DIM + j] = acc[i] + bias;
    }
}

extern "C" void kernel_launch(void* const* d_in, const int* in_sizes, int n_in,
                              void* d_out, int out_size, void* d_ws, size_t ws_size,
                              hipStream_t stream) {
    const float* x  = (const float*)d_in[0];
    const int*   ei = (const int*)d_in[1];      // [2, NE]: row0 = tgt, row1 = src
    const float* Wq = (const float*)d_in[2];
    const float* bq = (const float*)d_in[3];
    const float* Wk = (const float*)d_in[4];
    const float* bk = (const float*)d_in[5];
    const float* Wv = (const float*)d_in[6];
    const float* bv = (const float*)d_in[7];
    const float* Wo = (const float*)d_in[8];
    const float* bo = (const float*)d_in[9];

    const int* tgt = ei;
    const int* src = ei + NE;

    char* ws = (char*)d_ws;
    const size_t SZ_NODE = (size_t)NN * DIM * sizeof(float);   // 25.6 MB

    float* q   = (float*)(ws);
    float* k   = (float*)(ws + SZ_NODE);
    float* v   = (float*)(ws + 2 * SZ_NODE);
    float* agg = (float*)(ws + 3 * SZ_NODE);
    int*   cnt      = (int*)(ws + 4 * SZ_NODE);
    int*   off      = (int*)(ws + 4 * SZ_NODE + (size_t)NN * 4);
    int*   cursor   = (int*)(ws + 4 * SZ_NODE + (size_t)(2 * NN + 1) * 4);
    int*   edge_src = (int*)(ws + 4 * SZ_NODE + (size_t)(3 * NN + 1) * 4);

    const int node_blocks = (NN + 31) / 32;    // 1563
    const int edge_blocks = (NE + 255) / 256;  // 3125

    qkv_init_kernel<<<node_blocks, 256, 0, stream>>>(
        x, Wq, bq, Wk, bk, Wv, bv, q, k, v, cnt);
    hist_kernel<<<edge_blocks, 256, 0, stream>>>(tgt, cnt);
    scan_kernel<<<1, 1024, 0, stream>>>(cnt, off, cursor);
    fill_kernel<<<edge_blocks, 256, 0, stream>>>(tgt, src, cursor, edge_src);
    attn_pull_kernel<<<(NN * 64 + 255) / 256, 256, 0, stream>>>(
        off, edge_src, q, k, v, agg);
    outproj_kernel<<<node_blocks, 256, 0, stream>>>(agg, Wo, bo, (float*)d_out);
}